// Round 16
// baseline (63.465 us; speedup 1.0000x reference)
//
#include <hip/hip_runtime.h>
#include <hip/hip_fp16.h>

#define NB 32
#define NTT 4096
#define ND 256
#define NK 64
#define CHUNK 32
#define THREADS 256
#define PSPLIT 32

typedef __attribute__((ext_vector_type(8))) short short8;
typedef __attribute__((ext_vector_type(4))) float f32x4;

__device__ __forceinline__ unsigned short f2h(float f) {
    return __half_as_ushort(__float2half(f));
}
__device__ __forceinline__ unsigned int pkrtz(float a, float b) {
    union { __fp16 __attribute__((ext_vector_type(2))) v; unsigned int u; } x;
    x.v = __builtin_amdgcn_cvt_pkrtz(a, b);
    return x.u;
}
__device__ __forceinline__ short8 mk8(unsigned int a, unsigned int b,
                                      unsigned int c, unsigned int d) {
    union { unsigned int u[4]; short8 s; } x;
    x.u[0] = a; x.u[1] = b; x.u[2] = c; x.u[3] = d; return x.s;
}

// LDS-visibility-only barrier (keeps global loads in flight across rendezvous).
__device__ __forceinline__ void lds_barrier() {
    asm volatile("s_waitcnt lgkmcnt(0)" ::: "memory");
    __builtin_amdgcn_s_barrier();
}

// ---- LDS layout (bytes), total 40960 -> EXACTLY 4 WGs/CU (160 KB) ----
// WT : [64 k][256 d] fp16 : k*512 + ((2d) ^ ((k&15)<<4))       (32 KB)
// AT : 2 x [64 k][32 t] fp16 : k*64 + ((2t) ^ ((k&3)<<4))      (2 x 4 KB)
//      (16B-granular swizzle keeps GEMM2's ds_read_b128 aligned)
#define WT_OFF 0
#define AT_OFF 32768
#define SM_BYTES 40960

__device__ __forceinline__ int wt_byte(int k, int d) { return WT_OFF + k * 512 + ((2 * d) ^ ((k & 15) << 4)); }
__device__ __forceinline__ int at_byte(int buf, int k, int t) { return AT_OFF + buf * 4096 + k * 64 + ((2 * t) ^ ((k & 3) << 4)); }

// Fused: logits = x@W + b ; A = softmax_k ; Spart += A^T @ x ; spart = colsum(A)
// 4-WGs/CU TLP test with ALL discovered constraints satisfied:
//  - L2 window: 128 WGs/XCD x 32KB chunk = 4 MB (the working R6 ratio; R13's 6MB thrashed)
//  - VGPR: launch_bounds(256,2) (min-waves>=4 squeezes to 64 -> spill, R9/R10);
//    cv halved to 32 floats -> live state < R6's 128.
// GEMM1 for a 32-row chunk: wave computes 8 unique rows (lanes 8-15 duplicate
// lanes 0-7; loads coalesce, MFMA pipe ~4% busy so duplication is free);
// only lo<8 lanes write AT. GEMM2: single K=32 slice, wave d-strip of 64.
__global__ __launch_bounds__(THREADS, 2) void nv_k1(const float* __restrict__ x,
                                                    const float* __restrict__ aw,
                                                    const float* __restrict__ ab,
                                                    __half* __restrict__ Sp,
                                                    float* __restrict__ sp,
                                                    int P) {
    __shared__ char SM[SM_BYTES];
    const int tid  = threadIdx.x;
    const int w    = tid >> 6;        // wave 0..3
    const int lane = tid & 63;
    const int lo   = lane & 15;
    const int hi   = lane >> 4;
    const int wg   = blockIdx.x;
    const int b    = wg / P;
    const int p    = wg % P;
    const int rowsPer = NTT / P;
    const int nch  = rowsPer / CHUNK;

    // ---- stage W^T, coalesced f32x4 over k: thread -> (d, 4k) ----
#pragma unroll
    for (int it = 0; it < 16; ++it) {
        int f4 = it * THREADS + tid;     // f32x4 index into aw
        int d  = f4 >> 4;                // 16 f32x4 per d-row
        int k4 = (f4 & 15) * 4;
        f32x4 v = *(const f32x4*)(aw + (size_t)f4 * 4);
#pragma unroll
        for (int j = 0; j < 4; ++j)
            *(unsigned short*)(SM + wt_byte(k4 + j, d)) = f2h(v[j]);
    }
    __syncthreads();

    // S accumulator: wave w owns d-strip [64w, 64w+64), all 64 k rows
    f32x4 Sacc[4][4];
#pragma unroll
    for (int mt = 0; mt < 4; ++mt)
#pragma unroll
        for (int nt = 0; nt < 4; ++nt) Sacc[mt][nt] = (f32x4){0.f, 0.f, 0.f, 0.f};
    f32x4 acc_cs[4];
#pragma unroll
    for (int mt = 0; mt < 4; ++mt) acc_cs[mt] = (f32x4){0.f, 0.f, 0.f, 0.f};

    short8 ones;
#pragma unroll
    for (int j = 0; j < 8; ++j) ones[j] = (short)0x3C00;

    const float* xb = x + (size_t)b * NTT * ND;

    for (int c = 0; c < nch; ++c) {
        const int t0  = p * rowsPer + c * CHUNK;
        const int buf = c & 1;

        // ---- row loads + cvt: lane owns row t0 + 8w + (lo&7), d-quarter hi ----
        // (lanes lo>=8 duplicate lo-8: same address -> coalesced/L1-broadcast)
        const float* rowp = xb + (size_t)(t0 + 8 * w + (lo & 7)) * ND;
        short8 rf16[8];
#pragma unroll
        for (int ds = 0; ds < 8; ++ds) {
            f32x4 a  = *(const f32x4*)(rowp + 32 * ds + 8 * hi);
            f32x4 b2 = *(const f32x4*)(rowp + 32 * ds + 8 * hi + 4);
            rf16[ds] = mk8(pkrtz(a[0], a[1]), pkrtz(a[2], a[3]),
                           pkrtz(b2[0], b2[1]), pkrtz(b2[2], b2[3]));
        }

        // ---- GEMM1 (swapped): acc init = bias; lane -> 16 logits of its row ----
        f32x4 acc1[4];
#pragma unroll
        for (int mt = 0; mt < 4; ++mt)
            acc1[mt] = *(const f32x4*)(ab + 16 * mt + 4 * hi);
#pragma unroll
        for (int ds = 0; ds < 8; ++ds) {
#pragma unroll
            for (int mt = 0; mt < 4; ++mt) {
                short8 wf = *(const short8*)(SM + wt_byte(16 * mt + lo, 32 * ds + 8 * hi));
                acc1[mt] = __builtin_amdgcn_mfma_f32_16x16x32_f16(wf, rf16[ds], acc1[mt], 0, 0, 0);
            }
        }

        // ---- issue GEMM2 column loads for this chunk (32 scalar, L2-hot) ----
        // cv[nt*8+j] = X[t0 + 8hi + j][64w + 16nt + lo]
        float cv[32];
#pragma unroll
        for (int nt = 0; nt < 4; ++nt)
#pragma unroll
            for (int j = 0; j < 8; ++j)
                cv[nt * 8 + j] = xb[(size_t)(t0 + 8 * hi + j) * ND + 64 * w + 16 * nt + lo];

        // ---- softmax over k: lane holds 16 logits (k = 16mt+4hi+r) ----
        {
            float m = -3.0e38f;
#pragma unroll
            for (int mt = 0; mt < 4; ++mt)
#pragma unroll
                for (int r = 0; r < 4; ++r) m = fmaxf(m, acc1[mt][r]);
            m = fmaxf(m, __shfl_xor(m, 16));
            m = fmaxf(m, __shfl_xor(m, 32));
            float s = 0.f;
#pragma unroll
            for (int mt = 0; mt < 4; ++mt)
#pragma unroll
                for (int r = 0; r < 4; ++r) {
                    float e = __expf(acc1[mt][r] - m);
                    acc1[mt][r] = e;
                    s += e;
                }
            s += __shfl_xor(s, 16);
            s += __shfl_xor(s, 32);
            float inv = 1.0f / s;
            // write A^T (unique rows only): AT[k=16mt+4hi+r][t=8w+lo], lo<8
            if (lo < 8) {
#pragma unroll
                for (int mt = 0; mt < 4; ++mt)
#pragma unroll
                    for (int r = 0; r < 4; ++r) {
                        unsigned short h = f2h(acc1[mt][r] * inv);
                        *(unsigned short*)(SM + at_byte(buf, 16 * mt + 4 * hi + r, 8 * w + lo)) = h;
                    }
            }
        }
        lds_barrier();   // LDS-visibility barrier; global col loads stay in flight

        // ---- GEMM2: S[k][d] += A^T[k][t] X[t][d]; single K=32 slice ----
        {
            short8 af[4];
#pragma unroll
            for (int mt = 0; mt < 4; ++mt)
                af[mt] = *(const short8*)(SM + at_byte(buf, 16 * mt + lo, 8 * hi));
            if (w == 0) {
#pragma unroll
                for (int mt = 0; mt < 4; ++mt)
                    acc_cs[mt] = __builtin_amdgcn_mfma_f32_16x16x32_f16(af[mt], ones, acc_cs[mt], 0, 0, 0);
            }
#pragma unroll
            for (int nt = 0; nt < 4; ++nt) {
                short8 bf = mk8(pkrtz(cv[nt * 8 + 0], cv[nt * 8 + 1]),
                                pkrtz(cv[nt * 8 + 2], cv[nt * 8 + 3]),
                                pkrtz(cv[nt * 8 + 4], cv[nt * 8 + 5]),
                                pkrtz(cv[nt * 8 + 6], cv[nt * 8 + 7]));
#pragma unroll
                for (int mt = 0; mt < 4; ++mt)
                    Sacc[mt][nt] = __builtin_amdgcn_mfma_f32_16x16x32_f16(af[mt], bf, Sacc[mt][nt], 0, 0, 0);
            }
        }
    }

    // ---- colsum write (wave 0; all output cols identical, take lo==0) ----
    if (w == 0 && lo == 0) {
#pragma unroll
        for (int mt = 0; mt < 4; ++mt)
#pragma unroll
            for (int r = 0; r < 4; ++r)
                sp[(size_t)wg * 64 + 16 * mt + 4 * hi + r] = acc_cs[mt][r];
    }

    // ---- write partial S (fp16, sector-packed): per (mt,r): ushort4 of 4 nt ----
    // layout offset within row: w*64 + lo*4 + nt   (bijective in d = 64w+16nt+lo)
#pragma unroll
    for (int mt = 0; mt < 4; ++mt)
#pragma unroll
        for (int r = 0; r < 4; ++r) {
            int kc = 16 * mt + 4 * hi + r;
            unsigned long long pk =
                  (unsigned long long)f2h(Sacc[mt][0][r])
                | ((unsigned long long)f2h(Sacc[mt][1][r]) << 16)
                | ((unsigned long long)f2h(Sacc[mt][2][r]) << 32)
                | ((unsigned long long)f2h(Sacc[mt][3][r]) << 48);
            *(unsigned long long*)(Sp + ((size_t)wg * 64 + kc) * 256 + w * 64 + lo * 4) = pk;
        }
}

// Reduce fp16 packed partials, subtract colsum*centroid, L2-normalize per (b,k).
// P is a template parameter: reduce loops fully unroll (one latency wait).
template<int PP>
__global__ __launch_bounds__(256) void nv_k2t(const __half* __restrict__ Sp,
                                              const float* __restrict__ sp,
                                              const float* __restrict__ cent,
                                              float* __restrict__ out) {
    const int bk = blockIdx.x;
    const int b  = bk >> 6;
    const int k  = bk & 63;
    const int d  = threadIdx.x;
    // inverse of k1 packing: d = 64w+16nt+lo -> off = w*64 + lo*4 + nt
    const int off = (d >> 6) * 64 + (d & 15) * 4 + ((d >> 4) & 3);

    float cvc = cent[k * 256 + d];   // independent load, issued early

    float s = 0.f;
#pragma unroll
    for (int p = 0; p < PP; ++p)
        s += __half2float(Sp[(((size_t)(b * PP + p)) * 64 + k) * 256 + off]);
    float cv = 0.f;
#pragma unroll
    for (int p = 0; p < PP; ++p)
        cv += sp[(size_t)(b * PP + p) * 64 + k];

    float v = s - cv * cvc;

    float ss = v * v;
    ss += __shfl_xor(ss, 1);
    ss += __shfl_xor(ss, 2);
    ss += __shfl_xor(ss, 4);
    ss += __shfl_xor(ss, 8);
    ss += __shfl_xor(ss, 16);
    ss += __shfl_xor(ss, 32);
    __shared__ float red[4];
    const int wv = threadIdx.x >> 6, ln = threadIdx.x & 63;
    if (ln == 0) red[wv] = ss;
    __syncthreads();
    float tot = red[0] + red[1] + red[2] + red[3];
    float rn = 1.0f / fmaxf(sqrtf(tot), 1e-12f);
    out[((size_t)b * 64 + k) * 256 + d] = v * rn;
}

extern "C" void kernel_launch(void* const* d_in, const int* in_sizes, int n_in,
                              void* d_out, int out_size, void* d_ws, size_t ws_size,
                              hipStream_t stream) {
    (void)in_sizes; (void)n_in; (void)out_size;
    const float* x  = (const float*)d_in[0];
    const float* ct = (const float*)d_in[1];
    const float* aw = (const float*)d_in[2];
    const float* ab = (const float*)d_in[3];
    float* out = (float*)d_out;

    const size_t SP_ELEMS = (size_t)NB * NK * ND;   // per partial set (fp16)
    int P = PSPLIT;
    size_t need = (size_t)P * (SP_ELEMS * sizeof(__half) + (size_t)NB * NK * sizeof(float));
    while (P > 1 && need > ws_size) {
        P >>= 1;
        need = (size_t)P * (SP_ELEMS * sizeof(__half) + (size_t)NB * NK * sizeof(float));
    }
    __half* Sp = (__half*)d_ws;
    float*  sp = (float*)((char*)d_ws + (size_t)P * SP_ELEMS * sizeof(__half));

    nv_k1<<<dim3(NB * P), dim3(THREADS), 0, stream>>>(x, aw, ab, Sp, sp, P);

    switch (P) {
        case 32: nv_k2t<32><<<dim3(NB * NK), dim3(256), 0, stream>>>(Sp, sp, ct, out); break;
        case 16: nv_k2t<16><<<dim3(NB * NK), dim3(256), 0, stream>>>(Sp, sp, ct, out); break;
        case 8:  nv_k2t<8> <<<dim3(NB * NK), dim3(256), 0, stream>>>(Sp, sp, ct, out); break;
        case 4:  nv_k2t<4> <<<dim3(NB * NK), dim3(256), 0, stream>>>(Sp, sp, ct, out); break;
        case 2:  nv_k2t<2> <<<dim3(NB * NK), dim3(256), 0, stream>>>(Sp, sp, ct, out); break;
        default: nv_k2t<1> <<<dim3(NB * NK), dim3(256), 0, stream>>>(Sp, sp, ct, out); break;
    }
}

// Round 17
// 43.767 us; speedup vs baseline: 1.4501x; 1.4501x over previous
//
#include <hip/hip_runtime.h>
#include <hip/hip_fp16.h>

#define NB 32
#define NTT 4096
#define ND 256
#define NK 64
#define CHUNK 64
#define THREADS 256
#define PSPLIT 16

typedef __attribute__((ext_vector_type(8))) short short8;
typedef __attribute__((ext_vector_type(4))) float f32x4;

__device__ __forceinline__ unsigned short f2h(float f) {
    return __half_as_ushort(__float2half(f));
}
__device__ __forceinline__ unsigned int pkrtz(float a, float b) {
    union { __fp16 __attribute__((ext_vector_type(2))) v; unsigned int u; } x;
    x.v = __builtin_amdgcn_cvt_pkrtz(a, b);
    return x.u;
}
__device__ __forceinline__ short8 mk8(unsigned int a, unsigned int b,
                                      unsigned int c, unsigned int d) {
    union { unsigned int u[4]; short8 s; } x;
    x.u[0] = a; x.u[1] = b; x.u[2] = c; x.u[3] = d; return x.s;
}

// LDS-visibility-only barrier (keeps global loads in flight across rendezvous).
__device__ __forceinline__ void lds_barrier() {
    asm volatile("s_waitcnt lgkmcnt(0)" ::: "memory");
    __builtin_amdgcn_s_barrier();
}

// ---- LDS layout (bytes) ----
// WT : [64 k][256 d] fp16 : k*512 + ((2d) ^ ((k&15)<<4))   (32 KB)
// AT : 2 x [64 k][64 t] fp16 : k*128 + ((2t) ^ ((k&7)<<4)) (2 x 8 KB)
#define WT_OFF 0
#define AT_OFF 32768
#define SM_BYTES 49152

__device__ __forceinline__ int wt_byte(int k, int d) { return WT_OFF + k * 512 + ((2 * d) ^ ((k & 15) << 4)); }
__device__ __forceinline__ int at_byte(int buf, int k, int t) { return AT_OFF + buf * 8192 + k * 128 + ((2 * t) ^ ((k & 7) << 4)); }

// Fused: logits = x@W + b ; A = softmax_k ; Spart += A^T @ x ; spart = colsum(A)
// Best structure found (R15, 43.8 us). k1 ~= 40 us is the equilibrium of the
// 2-phase barrier structure; constraints documented across R7-R16:
//  - L2 window caps resident chunk-buffers at 2/CU (3-4 WG/CU thrash, R4/R13)
//  - unified VGPR: min-waves>=4 squeezes arch regs to 64 -> spill (R9/R10)
//  - source-level pipelining is compiler-defeated (R7)
//  - smaller chunks double per-chunk fixed costs (R16)
__global__ __launch_bounds__(THREADS, 2) void nv_k1(const float* __restrict__ x,
                                                    const float* __restrict__ aw,
                                                    const float* __restrict__ ab,
                                                    __half* __restrict__ Sp,
                                                    float* __restrict__ sp,
                                                    int P) {
    __shared__ char SM[SM_BYTES];
    const int tid  = threadIdx.x;
    const int w    = tid >> 6;        // wave 0..3
    const int lane = tid & 63;
    const int lo   = lane & 15;
    const int hi   = lane >> 4;
    const int wg   = blockIdx.x;
    const int b    = wg / P;
    const int p    = wg % P;
    const int rowsPer = NTT / P;
    const int nch  = rowsPer / CHUNK;

    // ---- stage W^T, coalesced f32x4 over k: thread -> (d, 4k) ----
#pragma unroll
    for (int it = 0; it < 16; ++it) {
        int f4 = it * THREADS + tid;     // f32x4 index into aw
        int d  = f4 >> 4;                // 16 f32x4 per d-row
        int k4 = (f4 & 15) * 4;
        f32x4 v = *(const f32x4*)(aw + (size_t)f4 * 4);
#pragma unroll
        for (int j = 0; j < 4; ++j)
            *(unsigned short*)(SM + wt_byte(k4 + j, d)) = f2h(v[j]);
    }
    __syncthreads();

    // S accumulator: wave w owns d-strip [64w, 64w+64), all 64 k rows
    f32x4 Sacc[4][4];
#pragma unroll
    for (int mt = 0; mt < 4; ++mt)
#pragma unroll
        for (int nt = 0; nt < 4; ++nt) Sacc[mt][nt] = (f32x4){0.f, 0.f, 0.f, 0.f};
    f32x4 acc_cs[4];
#pragma unroll
    for (int mt = 0; mt < 4; ++mt) acc_cs[mt] = (f32x4){0.f, 0.f, 0.f, 0.f};

    short8 ones;
#pragma unroll
    for (int j = 0; j < 8; ++j) ones[j] = (short)0x3C00;

    const float* xb = x + (size_t)b * NTT * ND;

    for (int c = 0; c < nch; ++c) {
        const int t0  = p * rowsPer + c * CHUNK;
        const int buf = c & 1;

        // ---- row-fragment loads + cvt: lane owns row t0+16w+lo, quarter hi ----
        const float* rowp = xb + (size_t)(t0 + 16 * w + lo) * ND;
        short8 rf16[8];
#pragma unroll
        for (int ds = 0; ds < 8; ++ds) {
            f32x4 a  = *(const f32x4*)(rowp + 32 * ds + 8 * hi);
            f32x4 b2 = *(const f32x4*)(rowp + 32 * ds + 8 * hi + 4);
            rf16[ds] = mk8(pkrtz(a[0], a[1]), pkrtz(a[2], a[3]),
                           pkrtz(b2[0], b2[1]), pkrtz(b2[2], b2[3]));
        }

        // ---- GEMM1 (swapped): acc init = bias; lane -> 16 logits of row 16w+lo ----
        f32x4 acc1[4];
#pragma unroll
        for (int mt = 0; mt < 4; ++mt)
            acc1[mt] = *(const f32x4*)(ab + 16 * mt + 4 * hi);
#pragma unroll
        for (int ds = 0; ds < 8; ++ds) {
#pragma unroll
            for (int mt = 0; mt < 4; ++mt) {
                short8 wf = *(const short8*)(SM + wt_byte(16 * mt + lo, 32 * ds + 8 * hi));
                acc1[mt] = __builtin_amdgcn_mfma_f32_16x16x32_f16(wf, rf16[ds], acc1[mt], 0, 0, 0);
            }
        }

        // ---- issue ALL GEMM2 column loads for this chunk (64 scalar) ----
        float cv0[32], cv1[32];
#pragma unroll
        for (int nt = 0; nt < 4; ++nt)
#pragma unroll
            for (int j = 0; j < 8; ++j)
                cv0[nt * 8 + j] = xb[(size_t)(t0 + 8 * hi + j) * ND + 64 * w + 16 * nt + lo];
#pragma unroll
        for (int nt = 0; nt < 4; ++nt)
#pragma unroll
            for (int j = 0; j < 8; ++j)
                cv1[nt * 8 + j] = xb[(size_t)(t0 + 32 + 8 * hi + j) * ND + 64 * w + 16 * nt + lo];

        // ---- softmax over k: lane holds 16 logits (k = 16mt+4hi+r) ----
        {
            float m = -3.0e38f;
#pragma unroll
            for (int mt = 0; mt < 4; ++mt)
#pragma unroll
                for (int r = 0; r < 4; ++r) m = fmaxf(m, acc1[mt][r]);
            m = fmaxf(m, __shfl_xor(m, 16));
            m = fmaxf(m, __shfl_xor(m, 32));
            float s = 0.f;
#pragma unroll
            for (int mt = 0; mt < 4; ++mt)
#pragma unroll
                for (int r = 0; r < 4; ++r) {
                    float e = __expf(acc1[mt][r] - m);
                    acc1[mt][r] = e;
                    s += e;
                }
            s += __shfl_xor(s, 16);
            s += __shfl_xor(s, 32);
            float inv = 1.0f / s;
            // write A^T: AT[k=16mt+4hi+r][t=16w+lo]
#pragma unroll
            for (int mt = 0; mt < 4; ++mt)
#pragma unroll
                for (int r = 0; r < 4; ++r) {
                    unsigned short h = f2h(acc1[mt][r] * inv);
                    *(unsigned short*)(SM + at_byte(buf, 16 * mt + 4 * hi + r, 16 * w + lo)) = h;
                }
        }
        lds_barrier();   // LDS-visibility barrier; global col loads stay in flight

        // ---- GEMM2: S[k][d] += A^T[k][t] X[t][d]; 2 t-slices of 32 ----
#pragma unroll
        for (int ts = 0; ts < 2; ++ts) {
            const float* cv = ts ? cv1 : cv0;
            short8 af[4];
#pragma unroll
            for (int mt = 0; mt < 4; ++mt)
                af[mt] = *(const short8*)(SM + at_byte(buf, 16 * mt + lo, 32 * ts + 8 * hi));
            if (w == 0) {
#pragma unroll
                for (int mt = 0; mt < 4; ++mt)
                    acc_cs[mt] = __builtin_amdgcn_mfma_f32_16x16x32_f16(af[mt], ones, acc_cs[mt], 0, 0, 0);
            }
#pragma unroll
            for (int nt = 0; nt < 4; ++nt) {
                short8 bf = mk8(pkrtz(cv[nt * 8 + 0], cv[nt * 8 + 1]),
                                pkrtz(cv[nt * 8 + 2], cv[nt * 8 + 3]),
                                pkrtz(cv[nt * 8 + 4], cv[nt * 8 + 5]),
                                pkrtz(cv[nt * 8 + 6], cv[nt * 8 + 7]));
#pragma unroll
                for (int mt = 0; mt < 4; ++mt)
                    Sacc[mt][nt] = __builtin_amdgcn_mfma_f32_16x16x32_f16(af[mt], bf, Sacc[mt][nt], 0, 0, 0);
            }
        }
    }

    // ---- colsum write (wave 0; all output cols identical, take lo==0) ----
    if (w == 0 && lo == 0) {
#pragma unroll
        for (int mt = 0; mt < 4; ++mt)
#pragma unroll
            for (int r = 0; r < 4; ++r)
                sp[(size_t)wg * 64 + 16 * mt + 4 * hi + r] = acc_cs[mt][r];
    }

    // ---- write partial S (fp16, sector-packed): per (mt,r): ushort4 of 4 nt ----
    // layout offset within row: w*64 + lo*4 + nt   (bijective in d = 64w+16nt+lo)
#pragma unroll
    for (int mt = 0; mt < 4; ++mt)
#pragma unroll
        for (int r = 0; r < 4; ++r) {
            int kc = 16 * mt + 4 * hi + r;
            unsigned long long pk =
                  (unsigned long long)f2h(Sacc[mt][0][r])
                | ((unsigned long long)f2h(Sacc[mt][1][r]) << 16)
                | ((unsigned long long)f2h(Sacc[mt][2][r]) << 32)
                | ((unsigned long long)f2h(Sacc[mt][3][r]) << 48);
            *(unsigned long long*)(Sp + ((size_t)wg * 64 + kc) * 256 + w * 64 + lo * 4) = pk;
        }
}

// Reduce fp16 packed partials, subtract colsum*centroid, L2-normalize per (b,k).
// P is a TEMPLATE parameter: both reduce loops fully unroll, so all PP Sp-loads
// issue back-to-back (one latency wait) instead of PP serial ~600cy waits.
template<int PP>
__global__ __launch_bounds__(256) void nv_k2t(const __half* __restrict__ Sp,
                                              const float* __restrict__ sp,
                                              const float* __restrict__ cent,
                                              float* __restrict__ out) {
    const int bk = blockIdx.x;
    const int b  = bk >> 6;
    const int k  = bk & 63;
    const int d  = threadIdx.x;
    // inverse of k1 packing: d = 64w+16nt+lo -> off = w*64 + lo*4 + nt
    const int off = (d >> 6) * 64 + (d & 15) * 4 + ((d >> 4) & 3);

    float cvc = cent[k * 256 + d];   // independent load, issued early

    float s = 0.f;
#pragma unroll
    for (int p = 0; p < PP; ++p)
        s += __half2float(Sp[(((size_t)(b * PP + p)) * 64 + k) * 256 + off]);
    float cv = 0.f;
#pragma unroll
    for (int p = 0; p < PP; ++p)
        cv += sp[(size_t)(b * PP + p) * 64 + k];

    float v = s - cv * cvc;

    float ss = v * v;
    ss += __shfl_xor(ss, 1);
    ss += __shfl_xor(ss, 2);
    ss += __shfl_xor(ss, 4);
    ss += __shfl_xor(ss, 8);
    ss += __shfl_xor(ss, 16);
    ss += __shfl_xor(ss, 32);
    __shared__ float red[4];
    const int wv = threadIdx.x >> 6, ln = threadIdx.x & 63;
    if (ln == 0) red[wv] = ss;
    __syncthreads();
    float tot = red[0] + red[1] + red[2] + red[3];
    float rn = 1.0f / fmaxf(sqrtf(tot), 1e-12f);
    out[((size_t)b * 64 + k) * 256 + d] = v * rn;
}

extern "C" void kernel_launch(void* const* d_in, const int* in_sizes, int n_in,
                              void* d_out, int out_size, void* d_ws, size_t ws_size,
                              hipStream_t stream) {
    (void)in_sizes; (void)n_in; (void)out_size;
    const float* x  = (const float*)d_in[0];
    const float* ct = (const float*)d_in[1];
    const float* aw = (const float*)d_in[2];
    const float* ab = (const float*)d_in[3];
    float* out = (float*)d_out;

    const size_t SP_ELEMS = (size_t)NB * NK * ND;   // per partial set (fp16)
    int P = PSPLIT;
    size_t need = (size_t)P * (SP_ELEMS * sizeof(__half) + (size_t)NB * NK * sizeof(float));
    while (P > 1 && need > ws_size) {
        P >>= 1;
        need = (size_t)P * (SP_ELEMS * sizeof(__half) + (size_t)NB * NK * sizeof(float));
    }
    __half* Sp = (__half*)d_ws;
    float*  sp = (float*)((char*)d_ws + (size_t)P * SP_ELEMS * sizeof(__half));

    nv_k1<<<dim3(NB * P), dim3(THREADS), 0, stream>>>(x, aw, ab, Sp, sp, P);

    switch (P) {
        case 16: nv_k2t<16><<<dim3(NB * NK), dim3(256), 0, stream>>>(Sp, sp, ct, out); break;
        case 8:  nv_k2t<8> <<<dim3(NB * NK), dim3(256), 0, stream>>>(Sp, sp, ct, out); break;
        case 4:  nv_k2t<4> <<<dim3(NB * NK), dim3(256), 0, stream>>>(Sp, sp, ct, out); break;
        case 2:  nv_k2t<2> <<<dim3(NB * NK), dim3(256), 0, stream>>>(Sp, sp, ct, out); break;
        default: nv_k2t<1> <<<dim3(NB * NK), dim3(256), 0, stream>>>(Sp, sp, ct, out); break;
    }
}